// Round 1
// baseline (2547.234 us; speedup 1.0000x reference)
//
#include <hip/hip_runtime.h>
#include <hip/hip_bf16.h>

#define NTHREADS 256

// ---------------- degree / normalization ----------------

__global__ __launch_bounds__(NTHREADS) void deg_count_kernel(
    const int* __restrict__ dst, float* __restrict__ deg, int E) {
  int i = blockIdx.x * blockDim.x + threadIdx.x;
  if (i < E) atomicAdd(&deg[dst[i]], 1.0f);
}

__global__ __launch_bounds__(NTHREADS) void deg_to_dis_kernel(
    float* __restrict__ deg, int n) {
  int i = blockIdx.x * blockDim.x + threadIdx.x;
  if (i < n) {
    float d = deg[i] + 1.0f;  // + self loop
    deg[i] = 1.0f / sqrtf(d);
  }
}

// ---------------- dense transform: out[n,128] = relu?(in)[n,128] @ W[128,128] ----------------

template <bool RELU_IN>
__global__ __launch_bounds__(NTHREADS) void gemm_kernel(
    const float* __restrict__ in, const float* __restrict__ W,
    float* __restrict__ out, int n) {
  __shared__ float Ws[128 * 128];       // 64 KB
  __shared__ float xs[32][128];         // 16 KB
  const int tid = threadIdx.x;

  // load W into LDS: 4096 float4 / 256 threads = 16 each
  const float4* W4 = (const float4*)W;
  float4* Ws4 = (float4*)Ws;
#pragma unroll
  for (int i = 0; i < 16; ++i) Ws4[tid + NTHREADS * i] = W4[tid + NTHREADS * i];

  const int row0 = blockIdx.x * 32;
  // load x tile: 1024 float4 / 256 threads = 4 each
#pragma unroll
  for (int i = 0; i < 4; ++i) {
    int idx = tid + NTHREADS * i;     // float4 index in tile
    int r = idx >> 5;                 // 32 float4 per row
    int c4 = idx & 31;
    int gr = row0 + r;
    float4 v = make_float4(0.f, 0.f, 0.f, 0.f);
    if (gr < n) v = ((const float4*)in)[gr * 32 + c4];
    if (RELU_IN) {
      v.x = fmaxf(v.x, 0.f); v.y = fmaxf(v.y, 0.f);
      v.z = fmaxf(v.z, 0.f); v.w = fmaxf(v.w, 0.f);
    }
    ((float4*)&xs[r][0])[c4] = v;
  }
  __syncthreads();

  const int wave = tid >> 6;
  const int lane = tid & 63;
  const int wr0 = wave * 8;  // 8 rows per wave

  float2 acc[8];
#pragma unroll
  for (int r = 0; r < 8; ++r) acc[r] = make_float2(0.f, 0.f);

  for (int k = 0; k < 128; ++k) {
    float2 w2 = *(const float2*)&Ws[k * 128 + lane * 2];
#pragma unroll
    for (int r = 0; r < 8; ++r) {
      float xv = xs[wr0 + r][k];
      acc[r].x = fmaf(xv, w2.x, acc[r].x);
      acc[r].y = fmaf(xv, w2.y, acc[r].y);
    }
  }

#pragma unroll
  for (int r = 0; r < 8; ++r) {
    int gr = row0 + wr0 + r;
    if (gr < n) *(float2*)&out[gr * 128 + lane * 2] = acc[r];
  }
}

// ---------------- aggregation init: out = h * dis^2 + b (self loop + bias) ----------------

__global__ __launch_bounds__(NTHREADS) void init_agg_kernel(
    const float* __restrict__ h, const float* __restrict__ dis,
    const float* __restrict__ b, float* __restrict__ out, int n) {
  int idx = blockIdx.x * blockDim.x + threadIdx.x;  // float4 granularity
  if (idx >= n * 32) return;
  int row = idx >> 5;
  int c4 = idx & 31;
  float d = dis[row];
  float dd = d * d;
  float4 v = ((const float4*)h)[idx];
  float4 bb = ((const float4*)b)[c4];
  float4 o = make_float4(fmaf(v.x, dd, bb.x), fmaf(v.y, dd, bb.y),
                         fmaf(v.z, dd, bb.z), fmaf(v.w, dd, bb.w));
  ((float4*)out)[idx] = o;
}

// ---------------- edge scatter: out[dst] += h[src] * dis[src]*dis[dst] ----------------

__global__ __launch_bounds__(NTHREADS) void edge_scatter_kernel(
    const float* __restrict__ h, float* __restrict__ out,
    const int* __restrict__ src, const int* __restrict__ dst,
    const float* __restrict__ dis, int E) {
  int wid = blockIdx.x * (NTHREADS / 64) + (threadIdx.x >> 6);
  int lane = threadIdx.x & 63;
  if (wid >= E) return;
  int s = src[wid];
  int d = dst[wid];
  float w = dis[s] * dis[d];
  float2 v = *(const float2*)&h[s * 128 + lane * 2];
  float* o = &out[d * 128 + lane * 2];
  atomicAdd(o, v.x * w);
  atomicAdd(o + 1, v.y * w);
}

// ---------------- pooling: sums[batch[i]] += h[i,:]; cnt[batch[i]] += 1 ----------------

__global__ __launch_bounds__(NTHREADS) void pool_kernel(
    const float* __restrict__ h, const int* __restrict__ batch,
    float* __restrict__ sums, float* __restrict__ cnt, int n) {
  int wid = blockIdx.x * (NTHREADS / 64) + (threadIdx.x >> 6);
  int lane = threadIdx.x & 63;
  if (wid >= n) return;
  int g = batch[wid];
  float2 v = *(const float2*)&h[wid * 128 + lane * 2];
  float* sp = &sums[g * 128 + lane * 2];
  atomicAdd(sp, v.x);
  atomicAdd(sp + 1, v.y);
  if (lane == 0) atomicAdd(&cnt[g], 1.0f);
}

// ---------------- final FC: out[g] = dot(sums[g]/max(cnt,1), fcW) + fcb ----------------

__global__ __launch_bounds__(64) void fc_kernel(
    const float* __restrict__ sums, const float* __restrict__ cnt,
    const float* __restrict__ fcW, const float* __restrict__ fcb,
    float* __restrict__ out) {
  int g = blockIdx.x;
  int lane = threadIdx.x;  // 64 threads
  float2 v = *(const float2*)&sums[g * 128 + lane * 2];
  float2 w = *(const float2*)&fcW[lane * 2];
  float p = v.x * w.x + v.y * w.y;
#pragma unroll
  for (int off = 32; off > 0; off >>= 1) p += __shfl_down(p, off);
  if (lane == 0) out[g] = p / fmaxf(cnt[g], 1.0f) + fcb[0];
}

extern "C" void kernel_launch(void* const* d_in, const int* in_sizes, int n_in,
                              void* d_out, int out_size, void* d_ws, size_t ws_size,
                              hipStream_t stream) {
  const float* x   = (const float*)d_in[0];
  const int* eidx  = (const int*)d_in[1];
  const int* batch = (const int*)d_in[2];
  const float* W0  = (const float*)d_in[3];
  const float* b0  = (const float*)d_in[4];
  const float* W1  = (const float*)d_in[5];
  const float* b1  = (const float*)d_in[6];
  const float* W2  = (const float*)d_in[7];
  const float* b2  = (const float*)d_in[8];
  const float* fcW = (const float*)d_in[9];
  const float* fcb = (const float*)d_in[10];
  float* out = (float*)d_out;

  const int N = in_sizes[0] / 128;
  const int E = in_sizes[1] / 2;
  const int G = out_size;

  const int* src = eidx;
  const int* dst = eidx + E;

  // workspace layout (floats)
  float* ws = (float*)d_ws;
  float* dis  = ws;                          // N
  float* bufG = ws + ((N + 255) & ~255);     // N*128 (gemm output)
  float* bufA = bufG + (size_t)N * 128;      // N*128 (aggregated)
  float* sums = bufA + (size_t)N * 128;      // G*128
  float* cnt  = sums + (size_t)G * 128;      // G

  hipMemsetAsync(dis, 0, (size_t)N * sizeof(float), stream);
  hipMemsetAsync(sums, 0, (size_t)(G * 128 + G) * sizeof(float), stream);

  // degree + normalization
  deg_count_kernel<<<(E + NTHREADS - 1) / NTHREADS, NTHREADS, 0, stream>>>(dst, dis, E);
  deg_to_dis_kernel<<<(N + NTHREADS - 1) / NTHREADS, NTHREADS, 0, stream>>>(dis, N);

  const int gemm_blocks = (N + 31) / 32;
  const int init_blocks = (N * 32 + NTHREADS - 1) / NTHREADS;
  const int edge_blocks = (E + 3) / 4;

  // layer 0
  gemm_kernel<false><<<gemm_blocks, NTHREADS, 0, stream>>>(x, W0, bufG, N);
  init_agg_kernel<<<init_blocks, NTHREADS, 0, stream>>>(bufG, dis, b0, bufA, N);
  edge_scatter_kernel<<<edge_blocks, NTHREADS, 0, stream>>>(bufG, bufA, src, dst, dis, E);

  // layer 1 (relu on input)
  gemm_kernel<true><<<gemm_blocks, NTHREADS, 0, stream>>>(bufA, W1, bufG, N);
  init_agg_kernel<<<init_blocks, NTHREADS, 0, stream>>>(bufG, dis, b1, bufA, N);
  edge_scatter_kernel<<<edge_blocks, NTHREADS, 0, stream>>>(bufG, bufA, src, dst, dis, E);

  // layer 2 (relu on input)
  gemm_kernel<true><<<gemm_blocks, NTHREADS, 0, stream>>>(bufA, W2, bufG, N);
  init_agg_kernel<<<init_blocks, NTHREADS, 0, stream>>>(bufG, dis, b2, bufA, N);
  edge_scatter_kernel<<<edge_blocks, NTHREADS, 0, stream>>>(bufG, bufA, src, dst, dis, E);

  // pool + fc
  pool_kernel<<<(N + 3) / 4, NTHREADS, 0, stream>>>(bufA, batch, sums, cnt, N);
  fc_kernel<<<G, 64, 0, stream>>>(sums, cnt, fcW, fcb, out);
}

// Round 2
// 891.844 us; speedup vs baseline: 2.8561x; 2.8561x over previous
//
#include <hip/hip_runtime.h>
#include <hip/hip_bf16.h>

#define NTHREADS 256

// ---------------- degree count (int) ----------------

__global__ __launch_bounds__(NTHREADS) void deg_count_kernel(
    const int* __restrict__ dst, int* __restrict__ degi, int E) {
  int i = blockIdx.x * blockDim.x + threadIdx.x;
  if (i < E) atomicAdd(&degi[dst[i]], 1);
}

__global__ __launch_bounds__(NTHREADS) void deg_to_dis_kernel(
    const int* __restrict__ degi, float* __restrict__ dis, int n) {
  int i = blockIdx.x * blockDim.x + threadIdx.x;
  if (i < n) {
    float d = (float)degi[i] + 1.0f;  // + self loop
    dis[i] = 1.0f / sqrtf(d);
  }
}

// ---------------- single-block exclusive scan over degi -> rowptr ----------------

__global__ __launch_bounds__(1024) void scan_kernel(
    const int* __restrict__ degi, int* __restrict__ rowptr, int n) {
  __shared__ int lds[1024];
  const int tid = threadIdx.x;
  const int per = (n + 1023) / 1024;
  const int start = tid * per;
  const int end = min(start + per, n);
  int s = 0;
  for (int i = start; i < end; ++i) s += degi[i];
  lds[tid] = s;
  __syncthreads();
  // Hillis-Steele inclusive scan
  for (int off = 1; off < 1024; off <<= 1) {
    int v = (tid >= off) ? lds[tid - off] : 0;
    __syncthreads();
    lds[tid] += v;
    __syncthreads();
  }
  int run = (tid == 0) ? 0 : lds[tid - 1];
  for (int i = start; i < end; ++i) {
    rowptr[i] = run;
    run += degi[i];
  }
  if (tid == 1023) rowptr[n] = run;
}

// ---------------- CSR fill: counting sort edges by dst ----------------

__global__ __launch_bounds__(NTHREADS) void fill_csr_kernel(
    const int* __restrict__ src, const int* __restrict__ dst,
    const float* __restrict__ dis, int* __restrict__ cursor,
    int* __restrict__ csr_src, float* __restrict__ csr_w, int E) {
  int e = blockIdx.x * blockDim.x + threadIdx.x;
  if (e >= E) return;
  int s = src[e];
  int d = dst[e];
  int p = atomicAdd(&cursor[d], 1);
  csr_src[p] = s;
  csr_w[p] = dis[s] * dis[d];
}

// ---------------- dense transform: out[n,128] = relu?(in)[n,128] @ W[128,128] ----------------

template <bool RELU_IN>
__global__ __launch_bounds__(NTHREADS) void gemm_kernel(
    const float* __restrict__ in, const float* __restrict__ W,
    float* __restrict__ out, int n) {
  __shared__ float Ws[128 * 128];       // 64 KB
  __shared__ float xs[32][128];         // 16 KB
  const int tid = threadIdx.x;

  const float4* W4 = (const float4*)W;
  float4* Ws4 = (float4*)Ws;
#pragma unroll
  for (int i = 0; i < 16; ++i) Ws4[tid + NTHREADS * i] = W4[tid + NTHREADS * i];

  const int row0 = blockIdx.x * 32;
#pragma unroll
  for (int i = 0; i < 4; ++i) {
    int idx = tid + NTHREADS * i;
    int r = idx >> 5;
    int c4 = idx & 31;
    int gr = row0 + r;
    float4 v = make_float4(0.f, 0.f, 0.f, 0.f);
    if (gr < n) v = ((const float4*)in)[gr * 32 + c4];
    if (RELU_IN) {
      v.x = fmaxf(v.x, 0.f); v.y = fmaxf(v.y, 0.f);
      v.z = fmaxf(v.z, 0.f); v.w = fmaxf(v.w, 0.f);
    }
    ((float4*)&xs[r][0])[c4] = v;
  }
  __syncthreads();

  const int wave = tid >> 6;
  const int lane = tid & 63;
  const int wr0 = wave * 8;

  float2 acc[8];
#pragma unroll
  for (int r = 0; r < 8; ++r) acc[r] = make_float2(0.f, 0.f);

  for (int k = 0; k < 128; ++k) {
    float2 w2 = *(const float2*)&Ws[k * 128 + lane * 2];
#pragma unroll
    for (int r = 0; r < 8; ++r) {
      float xv = xs[wr0 + r][k];
      acc[r].x = fmaf(xv, w2.x, acc[r].x);
      acc[r].y = fmaf(xv, w2.y, acc[r].y);
    }
  }

#pragma unroll
  for (int r = 0; r < 8; ++r) {
    int gr = row0 + wr0 + r;
    if (gr < n) *(float2*)&out[gr * 128 + lane * 2] = acc[r];
  }
}

// ---------------- fused aggregation (gather): out[i] = sum_{e->i} h[src]*w + h[i]*dis_i^2 + b ----------------

__global__ __launch_bounds__(NTHREADS) void agg_kernel(
    const float* __restrict__ h, const int* __restrict__ rowptr,
    const int* __restrict__ csr_src, const float* __restrict__ csr_w,
    const float* __restrict__ dis, const float* __restrict__ b,
    float* __restrict__ out, int n) {
  int node = blockIdx.x * (NTHREADS / 64) + (threadIdx.x >> 6);
  int lane = threadIdx.x & 63;
  if (node >= n) return;
  int r0 = rowptr[node];
  int r1 = rowptr[node + 1];
  float d = dis[node];

  float2 acc;
  {
    float2 v = *(const float2*)&h[(size_t)node * 128 + lane * 2];
    float2 bb = *(const float2*)&b[lane * 2];
    float dd = d * d;
    acc.x = fmaf(v.x, dd, bb.x);
    acc.y = fmaf(v.y, dd, bb.y);
  }

  int e = r0;
  for (; e + 1 < r1; e += 2) {
    int s0 = csr_src[e];
    int s1 = csr_src[e + 1];
    float w0 = csr_w[e];
    float w1 = csr_w[e + 1];
    float2 v0 = *(const float2*)&h[(size_t)s0 * 128 + lane * 2];
    float2 v1 = *(const float2*)&h[(size_t)s1 * 128 + lane * 2];
    acc.x = fmaf(v0.x, w0, acc.x);
    acc.y = fmaf(v0.y, w0, acc.y);
    acc.x = fmaf(v1.x, w1, acc.x);
    acc.y = fmaf(v1.y, w1, acc.y);
  }
  if (e < r1) {
    int s0 = csr_src[e];
    float w0 = csr_w[e];
    float2 v0 = *(const float2*)&h[(size_t)s0 * 128 + lane * 2];
    acc.x = fmaf(v0.x, w0, acc.x);
    acc.y = fmaf(v0.y, w0, acc.y);
  }

  *(float2*)&out[(size_t)node * 128 + lane * 2] = acc;
}

// ---------------- pooling ----------------

__global__ __launch_bounds__(NTHREADS) void pool_kernel(
    const float* __restrict__ h, const int* __restrict__ batch,
    float* __restrict__ sums, float* __restrict__ cnt, int n) {
  int wid = blockIdx.x * (NTHREADS / 64) + (threadIdx.x >> 6);
  int lane = threadIdx.x & 63;
  if (wid >= n) return;
  int g = batch[wid];
  float2 v = *(const float2*)&h[(size_t)wid * 128 + lane * 2];
  float* sp = &sums[g * 128 + lane * 2];
  atomicAdd(sp, v.x);
  atomicAdd(sp + 1, v.y);
  if (lane == 0) atomicAdd(&cnt[g], 1.0f);
}

// ---------------- final FC ----------------

__global__ __launch_bounds__(64) void fc_kernel(
    const float* __restrict__ sums, const float* __restrict__ cnt,
    const float* __restrict__ fcW, const float* __restrict__ fcb,
    float* __restrict__ out) {
  int g = blockIdx.x;
  int lane = threadIdx.x;
  float2 v = *(const float2*)&sums[g * 128 + lane * 2];
  float2 w = *(const float2*)&fcW[lane * 2];
  float p = v.x * w.x + v.y * w.y;
#pragma unroll
  for (int off = 32; off > 0; off >>= 1) p += __shfl_down(p, off);
  if (lane == 0) out[g] = p / fmaxf(cnt[g], 1.0f) + fcb[0];
}

extern "C" void kernel_launch(void* const* d_in, const int* in_sizes, int n_in,
                              void* d_out, int out_size, void* d_ws, size_t ws_size,
                              hipStream_t stream) {
  const float* x   = (const float*)d_in[0];
  const int* eidx  = (const int*)d_in[1];
  const int* batch = (const int*)d_in[2];
  const float* W0  = (const float*)d_in[3];
  const float* b0  = (const float*)d_in[4];
  const float* W1  = (const float*)d_in[5];
  const float* b1  = (const float*)d_in[6];
  const float* W2  = (const float*)d_in[7];
  const float* b2  = (const float*)d_in[8];
  const float* fcW = (const float*)d_in[9];
  const float* fcb = (const float*)d_in[10];
  float* out = (float*)d_out;

  const int N = in_sizes[0] / 128;
  const int E = in_sizes[1] / 2;
  const int G = out_size;

  const int* src = eidx;
  const int* dst = eidx + E;

  // workspace layout (4-byte units, 256-aligned sections)
  char* ws = (char*)d_ws;
  size_t off = 0;
  auto alloc = [&](size_t bytes) {
    void* p = ws + off;
    off = (off + bytes + 255) & ~(size_t)255;
    return p;
  };
  float* dis    = (float*)alloc((size_t)N * 4);
  int*   degi   = (int*)  alloc((size_t)N * 4);
  int*   rowptr = (int*)  alloc((size_t)(N + 1) * 4);
  int*   cursor = (int*)  alloc((size_t)N * 4);
  int*   csrsrc = (int*)  alloc((size_t)E * 4);
  float* csrw   = (float*)alloc((size_t)E * 4);
  float* bufG   = (float*)alloc((size_t)N * 128 * 4);
  float* bufA   = (float*)alloc((size_t)N * 128 * 4);
  float* sums   = (float*)alloc((size_t)G * 128 * 4);
  float* cnt    = (float*)alloc((size_t)G * 4);

  hipMemsetAsync(degi, 0, (size_t)N * sizeof(int), stream);
  hipMemsetAsync(sums, 0, (size_t)G * 128 * sizeof(float), stream);
  hipMemsetAsync(cnt, 0, (size_t)G * sizeof(float), stream);

  // CSR build
  deg_count_kernel<<<(E + NTHREADS - 1) / NTHREADS, NTHREADS, 0, stream>>>(dst, degi, E);
  deg_to_dis_kernel<<<(N + NTHREADS - 1) / NTHREADS, NTHREADS, 0, stream>>>(degi, dis, N);
  scan_kernel<<<1, 1024, 0, stream>>>(degi, rowptr, N);
  hipMemcpyAsync(cursor, rowptr, (size_t)N * sizeof(int), hipMemcpyDeviceToDevice, stream);
  fill_csr_kernel<<<(E + NTHREADS - 1) / NTHREADS, NTHREADS, 0, stream>>>(
      src, dst, dis, cursor, csrsrc, csrw, E);

  const int gemm_blocks = (N + 31) / 32;
  const int node_blocks = (N + 3) / 4;

  // layer 0
  gemm_kernel<false><<<gemm_blocks, NTHREADS, 0, stream>>>(x, W0, bufG, N);
  agg_kernel<<<node_blocks, NTHREADS, 0, stream>>>(bufG, rowptr, csrsrc, csrw, dis, b0, bufA, N);
  // layer 1
  gemm_kernel<true><<<gemm_blocks, NTHREADS, 0, stream>>>(bufA, W1, bufG, N);
  agg_kernel<<<node_blocks, NTHREADS, 0, stream>>>(bufG, rowptr, csrsrc, csrw, dis, b1, bufA, N);
  // layer 2
  gemm_kernel<true><<<gemm_blocks, NTHREADS, 0, stream>>>(bufA, W2, bufG, N);
  agg_kernel<<<node_blocks, NTHREADS, 0, stream>>>(bufG, rowptr, csrsrc, csrw, dis, b2, bufA, N);

  // pool + fc
  pool_kernel<<<node_blocks, NTHREADS, 0, stream>>>(bufA, batch, sums, cnt, N);
  fc_kernel<<<G, 64, 0, stream>>>(sums, cnt, fcW, fcb, out);
}

// Round 3
// 494.402 us; speedup vs baseline: 5.1522x; 1.8039x over previous
//
#include <hip/hip_runtime.h>
#include <hip/hip_bf16.h>

#define NTHREADS 256
#define POOL_CHUNK 32

// ---------------- degree count (int) ----------------

__global__ __launch_bounds__(NTHREADS) void deg_count_kernel(
    const int* __restrict__ dst, int* __restrict__ degi, int E) {
  int i = blockIdx.x * blockDim.x + threadIdx.x;
  if (i < E) atomicAdd(&degi[dst[i]], 1);
}

__global__ __launch_bounds__(NTHREADS) void deg_to_dis_kernel(
    const int* __restrict__ degi, float* __restrict__ dis, int n) {
  int i = blockIdx.x * blockDim.x + threadIdx.x;
  if (i < n) {
    float d = (float)degi[i] + 1.0f;  // + self loop
    dis[i] = 1.0f / sqrtf(d);
  }
}

// ---------------- single-block exclusive scan over degi -> rowptr ----------------

__global__ __launch_bounds__(1024) void scan_kernel(
    const int* __restrict__ degi, int* __restrict__ rowptr, int n) {
  __shared__ int lds[1024];
  const int tid = threadIdx.x;
  const int per = (n + 1023) / 1024;
  const int start = tid * per;
  const int end = min(start + per, n);
  int s = 0;
  for (int i = start; i < end; ++i) s += degi[i];
  lds[tid] = s;
  __syncthreads();
  for (int off = 1; off < 1024; off <<= 1) {
    int v = (tid >= off) ? lds[tid - off] : 0;
    __syncthreads();
    lds[tid] += v;
    __syncthreads();
  }
  int run = (tid == 0) ? 0 : lds[tid - 1];
  for (int i = start; i < end; ++i) {
    rowptr[i] = run;
    run += degi[i];
  }
  if (tid == 1023) rowptr[n] = run;
}

// ---------------- CSR fill: counting sort edges by dst ----------------

__global__ __launch_bounds__(NTHREADS) void fill_csr_kernel(
    const int* __restrict__ src, const int* __restrict__ dst,
    const float* __restrict__ dis, int* __restrict__ cursor,
    int* __restrict__ csr_src, float* __restrict__ csr_w, int E) {
  int e = blockIdx.x * blockDim.x + threadIdx.x;
  if (e >= E) return;
  int s = src[e];
  int d = dst[e];
  int p = atomicAdd(&cursor[d], 1);
  csr_src[p] = s;
  csr_w[p] = dis[s] * dis[d];
}

// ---------------- graph boundaries: gstart[g] = lower_bound(batch, g) ----------------

__global__ __launch_bounds__(128) void bounds_kernel(
    const int* __restrict__ batch, int* __restrict__ gstart, int n, int G) {
  int g = blockIdx.x * blockDim.x + threadIdx.x;
  if (g > G) return;
  int lo = 0, hi = n;
  while (lo < hi) {
    int mid = (lo + hi) >> 1;
    if (batch[mid] < g) lo = mid + 1; else hi = mid;
  }
  gstart[g] = lo;
}

// ---------------- dense transform: out[n,128] = relu?(in)[n,128] @ W[128,128] ----------------

template <bool RELU_IN>
__global__ __launch_bounds__(NTHREADS) void gemm_kernel(
    const float* __restrict__ in, const float* __restrict__ W,
    float* __restrict__ out, int n) {
  __shared__ float Ws[128 * 128];       // 64 KB
  __shared__ float xs[32][128];         // 16 KB
  const int tid = threadIdx.x;

  const float4* W4 = (const float4*)W;
  float4* Ws4 = (float4*)Ws;
#pragma unroll
  for (int i = 0; i < 16; ++i) Ws4[tid + NTHREADS * i] = W4[tid + NTHREADS * i];

  const int row0 = blockIdx.x * 32;
#pragma unroll
  for (int i = 0; i < 4; ++i) {
    int idx = tid + NTHREADS * i;
    int r = idx >> 5;
    int c4 = idx & 31;
    int gr = row0 + r;
    float4 v = make_float4(0.f, 0.f, 0.f, 0.f);
    if (gr < n) v = ((const float4*)in)[gr * 32 + c4];
    if (RELU_IN) {
      v.x = fmaxf(v.x, 0.f); v.y = fmaxf(v.y, 0.f);
      v.z = fmaxf(v.z, 0.f); v.w = fmaxf(v.w, 0.f);
    }
    ((float4*)&xs[r][0])[c4] = v;
  }
  __syncthreads();

  const int wave = tid >> 6;
  const int lane = tid & 63;
  const int wr0 = wave * 8;

  float2 acc[8];
#pragma unroll
  for (int r = 0; r < 8; ++r) acc[r] = make_float2(0.f, 0.f);

  for (int k = 0; k < 128; ++k) {
    float2 w2 = *(const float2*)&Ws[k * 128 + lane * 2];
#pragma unroll
    for (int r = 0; r < 8; ++r) {
      float xv = xs[wr0 + r][k];
      acc[r].x = fmaf(xv, w2.x, acc[r].x);
      acc[r].y = fmaf(xv, w2.y, acc[r].y);
    }
  }

#pragma unroll
  for (int r = 0; r < 8; ++r) {
    int gr = row0 + wr0 + r;
    if (gr < n) *(float2*)&out[gr * 128 + lane * 2] = acc[r];
  }
}

// ---------------- fused aggregation (gather) ----------------

__global__ __launch_bounds__(NTHREADS) void agg_kernel(
    const float* __restrict__ h, const int* __restrict__ rowptr,
    const int* __restrict__ csr_src, const float* __restrict__ csr_w,
    const float* __restrict__ dis, const float* __restrict__ b,
    float* __restrict__ out, int n) {
  int node = blockIdx.x * (NTHREADS / 64) + (threadIdx.x >> 6);
  int lane = threadIdx.x & 63;
  if (node >= n) return;
  int r0 = rowptr[node];
  int r1 = rowptr[node + 1];
  float d = dis[node];

  float2 acc;
  {
    float2 v = *(const float2*)&h[(size_t)node * 128 + lane * 2];
    float2 bb = *(const float2*)&b[lane * 2];
    float dd = d * d;
    acc.x = fmaf(v.x, dd, bb.x);
    acc.y = fmaf(v.y, dd, bb.y);
  }

  int e = r0;
  for (; e + 1 < r1; e += 2) {
    int s0 = csr_src[e];
    int s1 = csr_src[e + 1];
    float w0 = csr_w[e];
    float w1 = csr_w[e + 1];
    float2 v0 = *(const float2*)&h[(size_t)s0 * 128 + lane * 2];
    float2 v1 = *(const float2*)&h[(size_t)s1 * 128 + lane * 2];
    acc.x = fmaf(v0.x, w0, acc.x);
    acc.y = fmaf(v0.y, w0, acc.y);
    acc.x = fmaf(v1.x, w1, acc.x);
    acc.y = fmaf(v1.y, w1, acc.y);
  }
  if (e < r1) {
    int s0 = csr_src[e];
    float w0 = csr_w[e];
    float2 v0 = *(const float2*)&h[(size_t)s0 * 128 + lane * 2];
    acc.x = fmaf(v0.x, w0, acc.x);
    acc.y = fmaf(v0.y, w0, acc.y);
  }

  *(float2*)&out[(size_t)node * 128 + lane * 2] = acc;
}

// ---------------- pooling: chunked segment-sum (batch is sorted) ----------------

__global__ __launch_bounds__(NTHREADS) void pool_kernel(
    const float* __restrict__ h, const int* __restrict__ batch,
    float* __restrict__ sums, int n) {
  int wid = blockIdx.x * (NTHREADS / 64) + (threadIdx.x >> 6);
  int lane = threadIdx.x & 63;
  int i0 = wid * POOL_CHUNK;
  if (i0 >= n) return;
  int i1 = min(i0 + POOL_CHUNK, n);

  int g = batch[i0];
  float2 acc = make_float2(0.f, 0.f);
  for (int i = i0; i < i1; ++i) {
    int gi = batch[i];
    if (gi != g) {
      float* sp = &sums[g * 128 + lane * 2];
      atomicAdd(sp, acc.x);
      atomicAdd(sp + 1, acc.y);
      acc = make_float2(0.f, 0.f);
      g = gi;
    }
    float2 v = *(const float2*)&h[(size_t)i * 128 + lane * 2];
    acc.x += v.x;
    acc.y += v.y;
  }
  float* sp = &sums[g * 128 + lane * 2];
  atomicAdd(sp, acc.x);
  atomicAdd(sp + 1, acc.y);
}

// ---------------- final FC ----------------

__global__ __launch_bounds__(64) void fc_kernel(
    const float* __restrict__ sums, const int* __restrict__ gstart,
    const float* __restrict__ fcW, const float* __restrict__ fcb,
    float* __restrict__ out) {
  int g = blockIdx.x;
  int lane = threadIdx.x;
  float2 v = *(const float2*)&sums[g * 128 + lane * 2];
  float2 w = *(const float2*)&fcW[lane * 2];
  float p = v.x * w.x + v.y * w.y;
#pragma unroll
  for (int off = 32; off > 0; off >>= 1) p += __shfl_down(p, off);
  if (lane == 0) {
    float c = (float)(gstart[g + 1] - gstart[g]);
    out[g] = p / fmaxf(c, 1.0f) + fcb[0];
  }
}

extern "C" void kernel_launch(void* const* d_in, const int* in_sizes, int n_in,
                              void* d_out, int out_size, void* d_ws, size_t ws_size,
                              hipStream_t stream) {
  const float* x   = (const float*)d_in[0];
  const int* eidx  = (const int*)d_in[1];
  const int* batch = (const int*)d_in[2];
  const float* W0  = (const float*)d_in[3];
  const float* b0  = (const float*)d_in[4];
  const float* W1  = (const float*)d_in[5];
  const float* b1  = (const float*)d_in[6];
  const float* W2  = (const float*)d_in[7];
  const float* b2  = (const float*)d_in[8];
  const float* fcW = (const float*)d_in[9];
  const float* fcb = (const float*)d_in[10];
  float* out = (float*)d_out;

  const int N = in_sizes[0] / 128;
  const int E = in_sizes[1] / 2;
  const int G = out_size;

  const int* src = eidx;
  const int* dst = eidx + E;

  char* ws = (char*)d_ws;
  size_t off = 0;
  auto alloc = [&](size_t bytes) {
    void* p = ws + off;
    off = (off + bytes + 255) & ~(size_t)255;
    return p;
  };
  float* dis    = (float*)alloc((size_t)N * 4);
  int*   degi   = (int*)  alloc((size_t)N * 4);
  int*   rowptr = (int*)  alloc((size_t)(N + 1) * 4);
  int*   cursor = (int*)  alloc((size_t)N * 4);
  int*   csrsrc = (int*)  alloc((size_t)E * 4);
  float* csrw   = (float*)alloc((size_t)E * 4);
  float* bufG   = (float*)alloc((size_t)N * 128 * 4);
  float* bufA   = (float*)alloc((size_t)N * 128 * 4);
  float* sums   = (float*)alloc((size_t)G * 128 * 4);
  int*   gstart = (int*)  alloc((size_t)(G + 1) * 4);

  hipMemsetAsync(degi, 0, (size_t)N * sizeof(int), stream);
  hipMemsetAsync(sums, 0, (size_t)G * 128 * sizeof(float), stream);

  // CSR build + norm
  deg_count_kernel<<<(E + NTHREADS - 1) / NTHREADS, NTHREADS, 0, stream>>>(dst, degi, E);
  deg_to_dis_kernel<<<(N + NTHREADS - 1) / NTHREADS, NTHREADS, 0, stream>>>(degi, dis, N);
  scan_kernel<<<1, 1024, 0, stream>>>(degi, rowptr, N);
  hipMemcpyAsync(cursor, rowptr, (size_t)N * sizeof(int), hipMemcpyDeviceToDevice, stream);
  fill_csr_kernel<<<(E + NTHREADS - 1) / NTHREADS, NTHREADS, 0, stream>>>(
      src, dst, dis, cursor, csrsrc, csrw, E);
  bounds_kernel<<<1, 128, 0, stream>>>(batch, gstart, N, G);

  const int gemm_blocks = (N + 31) / 32;
  const int node_blocks = (N + 3) / 4;

  // layer 0
  gemm_kernel<false><<<gemm_blocks, NTHREADS, 0, stream>>>(x, W0, bufG, N);
  agg_kernel<<<node_blocks, NTHREADS, 0, stream>>>(bufG, rowptr, csrsrc, csrw, dis, b0, bufA, N);
  // layer 1
  gemm_kernel<true><<<gemm_blocks, NTHREADS, 0, stream>>>(bufA, W1, bufG, N);
  agg_kernel<<<node_blocks, NTHREADS, 0, stream>>>(bufG, rowptr, csrsrc, csrw, dis, b1, bufA, N);
  // layer 2
  gemm_kernel<true><<<gemm_blocks, NTHREADS, 0, stream>>>(bufA, W2, bufG, N);
  agg_kernel<<<node_blocks, NTHREADS, 0, stream>>>(bufG, rowptr, csrsrc, csrw, dis, b2, bufA, N);

  // pool + fc
  const int pool_waves = (N + POOL_CHUNK - 1) / POOL_CHUNK;
  pool_kernel<<<(pool_waves + 3) / 4, NTHREADS, 0, stream>>>(bufA, batch, sums, N);
  fc_kernel<<<G, 64, 0, stream>>>(sums, gstart, fcW, fcb, out);
}

// Round 4
// 427.342 us; speedup vs baseline: 5.9606x; 1.1569x over previous
//
#include <hip/hip_runtime.h>
#include <hip/hip_bf16.h>

#define NTHREADS 256
#define POOL_CHUNK 32
#define SCAN_CH 1024

// ---------------- degree count (int) ----------------

__global__ __launch_bounds__(NTHREADS) void deg_count_kernel(
    const int* __restrict__ dst, int* __restrict__ degi, int E) {
  int i = blockIdx.x * blockDim.x + threadIdx.x;
  if (i < E) atomicAdd(&degi[dst[i]], 1);
}

// ---------------- scan stage A: block partial sums + dis = rsqrt(deg+1) ----------------

__global__ __launch_bounds__(NTHREADS) void scan_part_kernel(
    const int* __restrict__ degi, float* __restrict__ dis,
    int* __restrict__ bsum, int n) {
  __shared__ int wsum[4];
  const int base = blockIdx.x * SCAN_CH;
  const int tid = threadIdx.x;
  int s = 0;
  for (int i = tid; i < SCAN_CH; i += NTHREADS) {
    int gi = base + i;
    if (gi < n) {
      int v = degi[gi];
      dis[gi] = rsqrtf((float)v + 1.0f);
      s += v;
    }
  }
#pragma unroll
  for (int off = 32; off > 0; off >>= 1) s += __shfl_down(s, off);
  if ((tid & 63) == 0) wsum[tid >> 6] = s;
  __syncthreads();
  if (tid == 0) bsum[blockIdx.x] = wsum[0] + wsum[1] + wsum[2] + wsum[3];
}

// ---------------- scan stage B: exclusive scan of block sums (nb <= 64) ----------------

__global__ __launch_bounds__(64) void scan_bsum_kernel(int* __restrict__ bsum, int nb) {
  int lane = threadIdx.x;
  int orig = (lane < nb) ? bsum[lane] : 0;
  int v = orig;
#pragma unroll
  for (int off = 1; off < 64; off <<= 1) {
    int u = __shfl_up(v, off);
    if (lane >= off) v += u;
  }
  if (lane < nb) bsum[lane] = v - orig;  // exclusive
}

// ---------------- scan stage C: final exclusive scan -> rowptr & cursor ----------------

__global__ __launch_bounds__(NTHREADS) void scan_write_kernel(
    const int* __restrict__ degi, const int* __restrict__ bsum,
    int* __restrict__ rowptr, int* __restrict__ cursor, int n, int E) {
  __shared__ int lds[SCAN_CH];
  __shared__ int tsum[NTHREADS];
  const int base = blockIdx.x * SCAN_CH;
  const int tid = threadIdx.x;
  for (int i = tid; i < SCAN_CH; i += NTHREADS) {
    int gi = base + i;
    lds[i] = (gi < n) ? degi[gi] : 0;
  }
  __syncthreads();
  const int K = SCAN_CH / NTHREADS;  // 4
  int s = 0;
#pragma unroll
  for (int j = 0; j < K; ++j) s += lds[tid * K + j];
  tsum[tid] = s;
  __syncthreads();
  for (int off = 1; off < NTHREADS; off <<= 1) {
    int v = (tid >= off) ? tsum[tid - off] : 0;
    __syncthreads();
    tsum[tid] += v;
    __syncthreads();
  }
  int run = bsum[blockIdx.x] + ((tid == 0) ? 0 : tsum[tid - 1]);
#pragma unroll
  for (int j = 0; j < K; ++j) {
    int gi = base + tid * K + j;
    if (gi < n) { rowptr[gi] = run; cursor[gi] = run; }
    run += lds[tid * K + j];
  }
  if (blockIdx.x == 0 && tid == 0) rowptr[n] = E;  // sum of in-degrees == E
}

// ---------------- CSR fill: counting sort edges by dst ----------------

__global__ __launch_bounds__(NTHREADS) void fill_csr_kernel(
    const int* __restrict__ src, const int* __restrict__ dst,
    const float* __restrict__ dis, int* __restrict__ cursor,
    int* __restrict__ csr_src, float* __restrict__ csr_w, int E) {
  int e = blockIdx.x * blockDim.x + threadIdx.x;
  if (e >= E) return;
  int s = src[e];
  int d = dst[e];
  int p = atomicAdd(&cursor[d], 1);
  csr_src[p] = s;
  csr_w[p] = dis[s] * dis[d];
}

// ---------------- graph boundaries: gstart[g] = lower_bound(batch, g) ----------------

__global__ __launch_bounds__(128) void bounds_kernel(
    const int* __restrict__ batch, int* __restrict__ gstart, int n, int G) {
  int g = blockIdx.x * blockDim.x + threadIdx.x;
  if (g > G) return;
  int lo = 0, hi = n;
  while (lo < hi) {
    int mid = (lo + hi) >> 1;
    if (batch[mid] < g) lo = mid + 1; else hi = mid;
  }
  gstart[g] = lo;
}

// ---------------- dense transform: out[n,128] = relu?(in)[n,128] @ W[128,128] ----------------

template <bool RELU_IN>
__global__ __launch_bounds__(NTHREADS) void gemm_kernel(
    const float* __restrict__ in, const float* __restrict__ W,
    float* __restrict__ out, int n) {
  __shared__ float Ws[128 * 128];       // 64 KB
  __shared__ float xs[32][128];         // 16 KB
  const int tid = threadIdx.x;

  const float4* W4 = (const float4*)W;
  float4* Ws4 = (float4*)Ws;
#pragma unroll
  for (int i = 0; i < 16; ++i) Ws4[tid + NTHREADS * i] = W4[tid + NTHREADS * i];

  const int row0 = blockIdx.x * 32;
#pragma unroll
  for (int i = 0; i < 4; ++i) {
    int idx = tid + NTHREADS * i;
    int r = idx >> 5;
    int c4 = idx & 31;
    int gr = row0 + r;
    float4 v = make_float4(0.f, 0.f, 0.f, 0.f);
    if (gr < n) v = ((const float4*)in)[gr * 32 + c4];
    if (RELU_IN) {
      v.x = fmaxf(v.x, 0.f); v.y = fmaxf(v.y, 0.f);
      v.z = fmaxf(v.z, 0.f); v.w = fmaxf(v.w, 0.f);
    }
    ((float4*)&xs[r][0])[c4] = v;
  }
  __syncthreads();

  const int wave = tid >> 6;
  const int lane = tid & 63;
  const int wr0 = wave * 8;

  float2 acc[8];
#pragma unroll
  for (int r = 0; r < 8; ++r) acc[r] = make_float2(0.f, 0.f);

  for (int k = 0; k < 128; ++k) {
    float2 w2 = *(const float2*)&Ws[k * 128 + lane * 2];
#pragma unroll
    for (int r = 0; r < 8; ++r) {
      float xv = xs[wr0 + r][k];
      acc[r].x = fmaf(xv, w2.x, acc[r].x);
      acc[r].y = fmaf(xv, w2.y, acc[r].y);
    }
  }

#pragma unroll
  for (int r = 0; r < 8; ++r) {
    int gr = row0 + wr0 + r;
    if (gr < n) *(float2*)&out[gr * 128 + lane * 2] = acc[r];
  }
}

// ---------------- fused aggregation (gather) ----------------

__global__ __launch_bounds__(NTHREADS) void agg_kernel(
    const float* __restrict__ h, const int* __restrict__ rowptr,
    const int* __restrict__ csr_src, const float* __restrict__ csr_w,
    const float* __restrict__ dis, const float* __restrict__ b,
    float* __restrict__ out, int n) {
  int node = blockIdx.x * (NTHREADS / 64) + (threadIdx.x >> 6);
  int lane = threadIdx.x & 63;
  if (node >= n) return;
  int r0 = rowptr[node];
  int r1 = rowptr[node + 1];
  float d = dis[node];

  float2 acc;
  {
    float2 v = *(const float2*)&h[(size_t)node * 128 + lane * 2];
    float2 bb = *(const float2*)&b[lane * 2];
    float dd = d * d;
    acc.x = fmaf(v.x, dd, bb.x);
    acc.y = fmaf(v.y, dd, bb.y);
  }

  int e = r0;
  for (; e + 1 < r1; e += 2) {
    int s0 = csr_src[e];
    int s1 = csr_src[e + 1];
    float w0 = csr_w[e];
    float w1 = csr_w[e + 1];
    float2 v0 = *(const float2*)&h[(size_t)s0 * 128 + lane * 2];
    float2 v1 = *(const float2*)&h[(size_t)s1 * 128 + lane * 2];
    acc.x = fmaf(v0.x, w0, acc.x);
    acc.y = fmaf(v0.y, w0, acc.y);
    acc.x = fmaf(v1.x, w1, acc.x);
    acc.y = fmaf(v1.y, w1, acc.y);
  }
  if (e < r1) {
    int s0 = csr_src[e];
    float w0 = csr_w[e];
    float2 v0 = *(const float2*)&h[(size_t)s0 * 128 + lane * 2];
    acc.x = fmaf(v0.x, w0, acc.x);
    acc.y = fmaf(v0.y, w0, acc.y);
  }

  *(float2*)&out[(size_t)node * 128 + lane * 2] = acc;
}

// ---------------- pooling: chunked segment-sum (batch is sorted) ----------------

__global__ __launch_bounds__(NTHREADS) void pool_kernel(
    const float* __restrict__ h, const int* __restrict__ batch,
    float* __restrict__ sums, int n) {
  int wid = blockIdx.x * (NTHREADS / 64) + (threadIdx.x >> 6);
  int lane = threadIdx.x & 63;
  int i0 = wid * POOL_CHUNK;
  if (i0 >= n) return;
  int i1 = min(i0 + POOL_CHUNK, n);

  int g = batch[i0];
  float2 acc = make_float2(0.f, 0.f);
  for (int i = i0; i < i1; ++i) {
    int gi = batch[i];
    if (gi != g) {
      float* sp = &sums[g * 128 + lane * 2];
      atomicAdd(sp, acc.x);
      atomicAdd(sp + 1, acc.y);
      acc = make_float2(0.f, 0.f);
      g = gi;
    }
    float2 v = *(const float2*)&h[(size_t)i * 128 + lane * 2];
    acc.x += v.x;
    acc.y += v.y;
  }
  float* sp = &sums[g * 128 + lane * 2];
  atomicAdd(sp, acc.x);
  atomicAdd(sp + 1, acc.y);
}

// ---------------- final FC ----------------

__global__ __launch_bounds__(64) void fc_kernel(
    const float* __restrict__ sums, const int* __restrict__ gstart,
    const float* __restrict__ fcW, const float* __restrict__ fcb,
    float* __restrict__ out) {
  int g = blockIdx.x;
  int lane = threadIdx.x;
  float2 v = *(const float2*)&sums[g * 128 + lane * 2];
  float2 w = *(const float2*)&fcW[lane * 2];
  float p = v.x * w.x + v.y * w.y;
#pragma unroll
  for (int off = 32; off > 0; off >>= 1) p += __shfl_down(p, off);
  if (lane == 0) {
    float c = (float)(gstart[g + 1] - gstart[g]);
    out[g] = p / fmaxf(c, 1.0f) + fcb[0];
  }
}

extern "C" void kernel_launch(void* const* d_in, const int* in_sizes, int n_in,
                              void* d_out, int out_size, void* d_ws, size_t ws_size,
                              hipStream_t stream) {
  const float* x   = (const float*)d_in[0];
  const int* eidx  = (const int*)d_in[1];
  const int* batch = (const int*)d_in[2];
  const float* W0  = (const float*)d_in[3];
  const float* b0  = (const float*)d_in[4];
  const float* W1  = (const float*)d_in[5];
  const float* b1  = (const float*)d_in[6];
  const float* W2  = (const float*)d_in[7];
  const float* b2  = (const float*)d_in[8];
  const float* fcW = (const float*)d_in[9];
  const float* fcb = (const float*)d_in[10];
  float* out = (float*)d_out;

  const int N = in_sizes[0] / 128;
  const int E = in_sizes[1] / 2;
  const int G = out_size;

  const int* src = eidx;
  const int* dst = eidx + E;

  char* ws = (char*)d_ws;
  size_t off = 0;
  auto alloc = [&](size_t bytes) {
    void* p = ws + off;
    off = (off + bytes + 255) & ~(size_t)255;
    return p;
  };
  float* dis    = (float*)alloc((size_t)N * 4);
  int*   degi   = (int*)  alloc((size_t)N * 4);
  int*   rowptr = (int*)  alloc((size_t)(N + 1) * 4);
  int*   cursor = (int*)  alloc((size_t)N * 4);
  int*   bsum   = (int*)  alloc(64 * 4);
  int*   csrsrc = (int*)  alloc((size_t)E * 4);
  float* csrw   = (float*)alloc((size_t)E * 4);
  float* bufG   = (float*)alloc((size_t)N * 128 * 4);
  float* bufA   = (float*)alloc((size_t)N * 128 * 4);
  float* sums   = (float*)alloc((size_t)G * 128 * 4);
  int*   gstart = (int*)  alloc((size_t)(G + 1) * 4);

  hipMemsetAsync(degi, 0, (size_t)N * sizeof(int), stream);
  hipMemsetAsync(sums, 0, (size_t)G * 128 * sizeof(float), stream);

  const int scan_blocks = (N + SCAN_CH - 1) / SCAN_CH;  // 49 for N=50000

  // CSR build + norm
  deg_count_kernel<<<(E + NTHREADS - 1) / NTHREADS, NTHREADS, 0, stream>>>(dst, degi, E);
  scan_part_kernel<<<scan_blocks, NTHREADS, 0, stream>>>(degi, dis, bsum, N);
  scan_bsum_kernel<<<1, 64, 0, stream>>>(bsum, scan_blocks);
  scan_write_kernel<<<scan_blocks, NTHREADS, 0, stream>>>(degi, bsum, rowptr, cursor, N, E);
  fill_csr_kernel<<<(E + NTHREADS - 1) / NTHREADS, NTHREADS, 0, stream>>>(
      src, dst, dis, cursor, csrsrc, csrw, E);
  bounds_kernel<<<1, 128, 0, stream>>>(batch, gstart, N, G);

  const int gemm_blocks = (N + 31) / 32;
  const int node_blocks = (N + 3) / 4;

  // layer 0
  gemm_kernel<false><<<gemm_blocks, NTHREADS, 0, stream>>>(x, W0, bufG, N);
  agg_kernel<<<node_blocks, NTHREADS, 0, stream>>>(bufG, rowptr, csrsrc, csrw, dis, b0, bufA, N);
  // layer 1
  gemm_kernel<true><<<gemm_blocks, NTHREADS, 0, stream>>>(bufA, W1, bufG, N);
  agg_kernel<<<node_blocks, NTHREADS, 0, stream>>>(bufG, rowptr, csrsrc, csrw, dis, b1, bufA, N);
  // layer 2
  gemm_kernel<true><<<gemm_blocks, NTHREADS, 0, stream>>>(bufA, W2, bufG, N);
  agg_kernel<<<node_blocks, NTHREADS, 0, stream>>>(bufG, rowptr, csrsrc, csrw, dis, b2, bufA, N);

  // pool + fc
  const int pool_waves = (N + POOL_CHUNK - 1) / POOL_CHUNK;
  pool_kernel<<<(pool_waves + 3) / 4, NTHREADS, 0, stream>>>(bufA, batch, sums, N);
  fc_kernel<<<G, 64, 0, stream>>>(sums, gstart, fcW, fcb, out);
}

// Round 5
// 358.161 us; speedup vs baseline: 7.1120x; 1.1932x over previous
//
#include <hip/hip_runtime.h>
#include <hip/hip_bf16.h>
#include <hip/hip_fp16.h>

#define NTHREADS 256
#define POOL_CHUNK 32
#define SCAN_CH 1024

// ---------------- degree count (int) ----------------

__global__ __launch_bounds__(NTHREADS) void deg_count_kernel(
    const int* __restrict__ dst, int* __restrict__ degi, int E) {
  int i = blockIdx.x * blockDim.x + threadIdx.x;
  if (i < E) atomicAdd(&degi[dst[i]], 1);
}

// ---------------- scan stage A: block partial sums + dis = rsqrt(deg+1) ----------------

__global__ __launch_bounds__(NTHREADS) void scan_part_kernel(
    const int* __restrict__ degi, float* __restrict__ dis,
    int* __restrict__ bsum, int n) {
  __shared__ int wsum[4];
  const int base = blockIdx.x * SCAN_CH;
  const int tid = threadIdx.x;
  int s = 0;
  for (int i = tid; i < SCAN_CH; i += NTHREADS) {
    int gi = base + i;
    if (gi < n) {
      int v = degi[gi];
      dis[gi] = rsqrtf((float)v + 1.0f);
      s += v;
    }
  }
#pragma unroll
  for (int off = 32; off > 0; off >>= 1) s += __shfl_down(s, off);
  if ((tid & 63) == 0) wsum[tid >> 6] = s;
  __syncthreads();
  if (tid == 0) bsum[blockIdx.x] = wsum[0] + wsum[1] + wsum[2] + wsum[3];
}

// ---------------- scan stage B: exclusive scan of block sums (nb <= 64) ----------------

__global__ __launch_bounds__(64) void scan_bsum_kernel(int* __restrict__ bsum, int nb) {
  int lane = threadIdx.x;
  int orig = (lane < nb) ? bsum[lane] : 0;
  int v = orig;
#pragma unroll
  for (int off = 1; off < 64; off <<= 1) {
    int u = __shfl_up(v, off);
    if (lane >= off) v += u;
  }
  if (lane < nb) bsum[lane] = v - orig;  // exclusive
}

// ---------------- scan stage C: final exclusive scan -> rowptr & cursor ----------------

__global__ __launch_bounds__(NTHREADS) void scan_write_kernel(
    const int* __restrict__ degi, const int* __restrict__ bsum,
    int* __restrict__ rowptr, int* __restrict__ cursor, int n, int E) {
  __shared__ int lds[SCAN_CH];
  __shared__ int tsum[NTHREADS];
  const int base = blockIdx.x * SCAN_CH;
  const int tid = threadIdx.x;
  for (int i = tid; i < SCAN_CH; i += NTHREADS) {
    int gi = base + i;
    lds[i] = (gi < n) ? degi[gi] : 0;
  }
  __syncthreads();
  const int K = SCAN_CH / NTHREADS;  // 4
  int s = 0;
#pragma unroll
  for (int j = 0; j < K; ++j) s += lds[tid * K + j];
  tsum[tid] = s;
  __syncthreads();
  for (int off = 1; off < NTHREADS; off <<= 1) {
    int v = (tid >= off) ? tsum[tid - off] : 0;
    __syncthreads();
    tsum[tid] += v;
    __syncthreads();
  }
  int run = bsum[blockIdx.x] + ((tid == 0) ? 0 : tsum[tid - 1]);
#pragma unroll
  for (int j = 0; j < K; ++j) {
    int gi = base + tid * K + j;
    if (gi < n) { rowptr[gi] = run; cursor[gi] = run; }
    run += lds[tid * K + j];
  }
  if (blockIdx.x == 0 && tid == 0) rowptr[n] = E;  // sum of in-degrees == E
}

// ---------------- CSR fill: counting sort edges by dst (src index only) ----------------

__global__ __launch_bounds__(NTHREADS) void fill_csr_kernel(
    const int* __restrict__ src, const int* __restrict__ dst,
    int* __restrict__ cursor, int* __restrict__ csr_src, int E) {
  int e = blockIdx.x * blockDim.x + threadIdx.x;
  if (e >= E) return;
  int s = src[e];
  int d = dst[e];
  int p = atomicAdd(&cursor[d], 1);
  csr_src[p] = s;
}

// ---------------- graph boundaries: gstart[g] = lower_bound(batch, g) ----------------

__global__ __launch_bounds__(128) void bounds_kernel(
    const int* __restrict__ batch, int* __restrict__ gstart, int n, int G) {
  int g = blockIdx.x * blockDim.x + threadIdx.x;
  if (g > G) return;
  int lo = 0, hi = n;
  while (lo < hi) {
    int mid = (lo + hi) >> 1;
    if (batch[mid] < g) lo = mid + 1; else hi = mid;
  }
  gstart[g] = lo;
}

// ---------------- dense transform: hs[n,128] = fp16( (relu?(in) @ W) * dis[row] ) ----------------

template <bool RELU_IN>
__global__ __launch_bounds__(NTHREADS) void gemm_kernel(
    const float* __restrict__ in, const float* __restrict__ W,
    const float* __restrict__ dis, __half2* __restrict__ out, int n) {
  __shared__ float Ws[128 * 128];       // 64 KB
  __shared__ float xs[32][128];         // 16 KB
  const int tid = threadIdx.x;

  const float4* W4 = (const float4*)W;
  float4* Ws4 = (float4*)Ws;
#pragma unroll
  for (int i = 0; i < 16; ++i) Ws4[tid + NTHREADS * i] = W4[tid + NTHREADS * i];

  const int row0 = blockIdx.x * 32;
#pragma unroll
  for (int i = 0; i < 4; ++i) {
    int idx = tid + NTHREADS * i;
    int r = idx >> 5;
    int c4 = idx & 31;
    int gr = row0 + r;
    float4 v = make_float4(0.f, 0.f, 0.f, 0.f);
    if (gr < n) v = ((const float4*)in)[gr * 32 + c4];
    if (RELU_IN) {
      v.x = fmaxf(v.x, 0.f); v.y = fmaxf(v.y, 0.f);
      v.z = fmaxf(v.z, 0.f); v.w = fmaxf(v.w, 0.f);
    }
    ((float4*)&xs[r][0])[c4] = v;
  }
  __syncthreads();

  const int wave = tid >> 6;
  const int lane = tid & 63;
  const int wr0 = wave * 8;

  float2 acc[8];
#pragma unroll
  for (int r = 0; r < 8; ++r) acc[r] = make_float2(0.f, 0.f);

  for (int k4 = 0; k4 < 32; ++k4) {
    float xv[8][4];
#pragma unroll
    for (int r = 0; r < 8; ++r)
      *(float4*)&xv[r][0] = *(const float4*)&xs[wr0 + r][k4 * 4];
#pragma unroll
    for (int kk = 0; kk < 4; ++kk) {
      float2 w2 = *(const float2*)&Ws[(k4 * 4 + kk) * 128 + lane * 2];
#pragma unroll
      for (int r = 0; r < 8; ++r) {
        acc[r].x = fmaf(xv[r][kk], w2.x, acc[r].x);
        acc[r].y = fmaf(xv[r][kk], w2.y, acc[r].y);
      }
    }
  }

#pragma unroll
  for (int r = 0; r < 8; ++r) {
    int gr = row0 + wr0 + r;
    if (gr < n) {
      float ds = dis[gr];
      out[(size_t)gr * 64 + lane] =
          __float22half2_rn(make_float2(acc[r].x * ds, acc[r].y * ds));
    }
  }
}

// ---------------- fused aggregation (gather, fp16 operand) ----------------
// out[i] = dis[i] * (hs[i] + sum_e hs[src_e]) + b     (hs already scaled by dis[src])

__global__ __launch_bounds__(NTHREADS) void agg_kernel(
    const __half2* __restrict__ hs, const int* __restrict__ rowptr,
    const int* __restrict__ csr_src, const float* __restrict__ dis,
    const float* __restrict__ b, float* __restrict__ out, int n) {
  int node = blockIdx.x * (NTHREADS / 64) + (threadIdx.x >> 6);
  int lane = threadIdx.x & 63;
  if (node >= n) return;
  int r0 = rowptr[node];
  int r1 = rowptr[node + 1];
  float di = dis[node];

  float2 acc = __half22float2(hs[(size_t)node * 64 + lane]);  // self loop
  float2 acc2 = make_float2(0.f, 0.f);

  int e = r0;
  for (; e + 3 < r1; e += 4) {
    int s0 = csr_src[e];
    int s1 = csr_src[e + 1];
    int s2 = csr_src[e + 2];
    int s3 = csr_src[e + 3];
    float2 v0 = __half22float2(hs[(size_t)s0 * 64 + lane]);
    float2 v1 = __half22float2(hs[(size_t)s1 * 64 + lane]);
    float2 v2 = __half22float2(hs[(size_t)s2 * 64 + lane]);
    float2 v3 = __half22float2(hs[(size_t)s3 * 64 + lane]);
    acc.x += v0.x; acc.y += v0.y;
    acc2.x += v1.x; acc2.y += v1.y;
    acc.x += v2.x; acc.y += v2.y;
    acc2.x += v3.x; acc2.y += v3.y;
  }
  for (; e < r1; ++e) {
    int s0 = csr_src[e];
    float2 v0 = __half22float2(hs[(size_t)s0 * 64 + lane]);
    acc.x += v0.x; acc.y += v0.y;
  }
  acc.x += acc2.x; acc.y += acc2.y;

  float2 bb = *(const float2*)&b[lane * 2];
  float2 res;
  res.x = fmaf(acc.x, di, bb.x);
  res.y = fmaf(acc.y, di, bb.y);
  *(float2*)&out[(size_t)node * 128 + lane * 2] = res;
}

// ---------------- pooling: chunked segment-sum (batch is sorted) ----------------

__global__ __launch_bounds__(NTHREADS) void pool_kernel(
    const float* __restrict__ h, const int* __restrict__ batch,
    float* __restrict__ sums, int n) {
  int wid = blockIdx.x * (NTHREADS / 64) + (threadIdx.x >> 6);
  int lane = threadIdx.x & 63;
  int i0 = wid * POOL_CHUNK;
  if (i0 >= n) return;
  int i1 = min(i0 + POOL_CHUNK, n);

  int g = batch[i0];
  float2 acc = make_float2(0.f, 0.f);
  for (int i = i0; i < i1; ++i) {
    int gi = batch[i];
    if (gi != g) {
      float* sp = &sums[g * 128 + lane * 2];
      atomicAdd(sp, acc.x);
      atomicAdd(sp + 1, acc.y);
      acc = make_float2(0.f, 0.f);
      g = gi;
    }
    float2 v = *(const float2*)&h[(size_t)i * 128 + lane * 2];
    acc.x += v.x;
    acc.y += v.y;
  }
  float* sp = &sums[g * 128 + lane * 2];
  atomicAdd(sp, acc.x);
  atomicAdd(sp + 1, acc.y);
}

// ---------------- final FC ----------------

__global__ __launch_bounds__(64) void fc_kernel(
    const float* __restrict__ sums, const int* __restrict__ gstart,
    const float* __restrict__ fcW, const float* __restrict__ fcb,
    float* __restrict__ out) {
  int g = blockIdx.x;
  int lane = threadIdx.x;
  float2 v = *(const float2*)&sums[g * 128 + lane * 2];
  float2 w = *(const float2*)&fcW[lane * 2];
  float p = v.x * w.x + v.y * w.y;
#pragma unroll
  for (int off = 32; off > 0; off >>= 1) p += __shfl_down(p, off);
  if (lane == 0) {
    float c = (float)(gstart[g + 1] - gstart[g]);
    out[g] = p / fmaxf(c, 1.0f) + fcb[0];
  }
}

extern "C" void kernel_launch(void* const* d_in, const int* in_sizes, int n_in,
                              void* d_out, int out_size, void* d_ws, size_t ws_size,
                              hipStream_t stream) {
  const float* x   = (const float*)d_in[0];
  const int* eidx  = (const int*)d_in[1];
  const int* batch = (const int*)d_in[2];
  const float* W0  = (const float*)d_in[3];
  const float* b0  = (const float*)d_in[4];
  const float* W1  = (const float*)d_in[5];
  const float* b1  = (const float*)d_in[6];
  const float* W2  = (const float*)d_in[7];
  const float* b2  = (const float*)d_in[8];
  const float* fcW = (const float*)d_in[9];
  const float* fcb = (const float*)d_in[10];
  float* out = (float*)d_out;

  const int N = in_sizes[0] / 128;
  const int E = in_sizes[1] / 2;
  const int G = out_size;

  const int* src = eidx;
  const int* dst = eidx + E;

  char* ws = (char*)d_ws;
  size_t off = 0;
  auto alloc = [&](size_t bytes) {
    void* p = ws + off;
    off = (off + bytes + 255) & ~(size_t)255;
    return p;
  };
  float*   dis    = (float*)  alloc((size_t)N * 4);
  int*     degi   = (int*)    alloc((size_t)N * 4);
  int*     rowptr = (int*)    alloc((size_t)(N + 1) * 4);
  int*     cursor = (int*)    alloc((size_t)N * 4);
  int*     bsum   = (int*)    alloc(64 * 4);
  int*     csrsrc = (int*)    alloc((size_t)E * 4);
  __half2* hsbuf  = (__half2*)alloc((size_t)N * 128 * 2);
  float*   bufA   = (float*)  alloc((size_t)N * 128 * 4);
  float*   sums   = (float*)  alloc((size_t)G * 128 * 4);
  int*     gstart = (int*)    alloc((size_t)(G + 1) * 4);

  hipMemsetAsync(degi, 0, (size_t)N * sizeof(int), stream);
  hipMemsetAsync(sums, 0, (size_t)G * 128 * sizeof(float), stream);

  const int scan_blocks = (N + SCAN_CH - 1) / SCAN_CH;  // 49 for N=50000

  // CSR build + norm
  deg_count_kernel<<<(E + NTHREADS - 1) / NTHREADS, NTHREADS, 0, stream>>>(dst, degi, E);
  scan_part_kernel<<<scan_blocks, NTHREADS, 0, stream>>>(degi, dis, bsum, N);
  scan_bsum_kernel<<<1, 64, 0, stream>>>(bsum, scan_blocks);
  scan_write_kernel<<<scan_blocks, NTHREADS, 0, stream>>>(degi, bsum, rowptr, cursor, N, E);
  fill_csr_kernel<<<(E + NTHREADS - 1) / NTHREADS, NTHREADS, 0, stream>>>(
      src, dst, cursor, csrsrc, E);
  bounds_kernel<<<1, 128, 0, stream>>>(batch, gstart, N, G);

  const int gemm_blocks = (N + 31) / 32;
  const int node_blocks = (N + 3) / 4;

  // layer 0
  gemm_kernel<false><<<gemm_blocks, NTHREADS, 0, stream>>>(x, W0, dis, hsbuf, N);
  agg_kernel<<<node_blocks, NTHREADS, 0, stream>>>(hsbuf, rowptr, csrsrc, dis, b0, bufA, N);
  // layer 1
  gemm_kernel<true><<<gemm_blocks, NTHREADS, 0, stream>>>(bufA, W1, dis, hsbuf, N);
  agg_kernel<<<node_blocks, NTHREADS, 0, stream>>>(hsbuf, rowptr, csrsrc, dis, b1, bufA, N);
  // layer 2
  gemm_kernel<true><<<gemm_blocks, NTHREADS, 0, stream>>>(bufA, W2, dis, hsbuf, N);
  agg_kernel<<<node_blocks, NTHREADS, 0, stream>>>(hsbuf, rowptr, csrsrc, dis, b2, bufA, N);

  // pool + fc
  const int pool_waves = (N + POOL_CHUNK - 1) / POOL_CHUNK;
  pool_kernel<<<(pool_waves + 3) / 4, NTHREADS, 0, stream>>>(bufA, batch, sums, N);
  fc_kernel<<<G, 64, 0, stream>>>(sums, gstart, fcW, fcb, out);
}